// Round 2
// baseline (1093.806 us; speedup 1.0000x reference)
//
#include <hip/hip_runtime.h>
#include <hip/hip_bf16.h>

typedef __hip_bfloat16 bf16;
typedef __attribute__((ext_vector_type(8))) short short8;
typedef __attribute__((ext_vector_type(4))) float float4v;

// ---- problem constants ----
#define N1 120000
#define N2 20000
#define N3 4000
#define E0 1800000
#define E1 200000
#define E2 20000
#define D_IN 128
#define D_HID 256
#define D_OUT 47

// bucket counts for the bucketed CSR fill (128 dsts per bucket)
#define NB0 938
#define NB1 157
#define NB2 32

__device__ __forceinline__ void stv(float* p, float v) { *p = v; }
__device__ __forceinline__ void stv(bf16* p, float v) { *p = __float2bfloat16(v); }

__device__ __forceinline__ unsigned short f2bu(float v) {
    union { bf16 h; unsigned short u; } c;
    c.h = __float2bfloat16(v);
    return c.u;
}
__device__ __forceinline__ short f2bs(float v) { return (short)f2bu(v); }
__device__ __forceinline__ float bu2f(unsigned short u) { return __uint_as_float(((unsigned)u) << 16); }

__device__ __forceinline__ short8 load8(const bf16* p) {
    union { uint4 u; short8 s; } r;
    r.u = *(const uint4*)p;
    return r.s;
}
__device__ __forceinline__ short8 load8(const float* p) {
    float4 a = *(const float4*)p;
    float4 b = *(const float4*)(p + 4);
    short8 s;
    s[0] = f2bs(a.x); s[1] = f2bs(a.y); s[2] = f2bs(a.z); s[3] = f2bs(a.w);
    s[4] = f2bs(b.x); s[5] = f2bs(b.y); s[6] = f2bs(b.z); s[7] = f2bs(b.w);
    return s;
}

// ================= x -> bf16 conversion =================
__global__ __launch_bounds__(256) void convert_x(const float* __restrict__ x,
                                                 bf16* __restrict__ xb, int n8) {
    int i = blockIdx.x * blockDim.x + threadIdx.x;
    if (i >= n8) return;
    const float* p = x + (size_t)i * 8;
    float4 a = *(const float4*)p;
    float4 b = *(const float4*)(p + 4);
    union { uint4 u; short s[8]; } o;
    o.s[0] = f2bs(a.x); o.s[1] = f2bs(a.y); o.s[2] = f2bs(a.z); o.s[3] = f2bs(a.w);
    o.s[4] = f2bs(b.x); o.s[5] = f2bs(b.y); o.s[6] = f2bs(b.z); o.s[7] = f2bs(b.w);
    *(uint4*)(xb + (size_t)i * 8) = o.u;
}

// ================= batched weight transpose+convert =================
// W[K][N] f32 -> Wt[Npad][K] bf16
__global__ void wt_batch(const float* W0s, const float* W0n, const float* W1s,
                         const float* W1n, const float* W2s, const float* W2n,
                         bf16* T0s, bf16* T0n, bf16* T1s, bf16* T1n, bf16* T2s, bf16* T2n) {
    int i = blockIdx.x * blockDim.x + threadIdx.x;
    const float* W; bf16* T; int K, N, j;
    if      (i <  32768) { W = W0s; T = T0s; K = 128; N = 256; j = i; }
    else if (i <  65536) { W = W0n; T = T0n; K = 128; N = 256; j = i - 32768; }
    else if (i < 131072) { W = W1s; T = T1s; K = 256; N = 256; j = i - 65536; }
    else if (i < 196608) { W = W1n; T = T1n; K = 256; N = 256; j = i - 131072; }
    else if (i < 208896) { W = W2s; T = T2s; K = 256; N = 47;  j = i - 196608; }
    else if (i < 221184) { W = W2n; T = T2n; K = 256; N = 47;  j = i - 208896; }
    else return;
    int n = j / K, k = j - n * K;
    float v = (n < N) ? W[(size_t)k * N + n] : 0.f;
    T[j] = __float2bfloat16(v);
}

// ================= batched CSR build =================
__global__ void hist_batch(const int* __restrict__ d0, const int* __restrict__ d1,
                           const int* __restrict__ d2, int* __restrict__ c0,
                           int* __restrict__ c1, int* __restrict__ c2) {
    int i = blockIdx.x * blockDim.x + threadIdx.x;
    if (i < E0) atomicAdd(&c0[d0[i]], 1);
    else if (i < E0 + E1) atomicAdd(&c1[d1[i - E0]], 1);
    else if (i < E0 + E1 + E2) atomicAdd(&c2[d2[i - E0 - E1]], 1);
}

// chunk=1024; layer chunk counts: 118 / 20 / 4 -> 142 blocks total
__global__ __launch_bounds__(256) void scan_chunk_batch(
    const int* __restrict__ c0, const int* __restrict__ c1, const int* __restrict__ c2,
    int* __restrict__ r0, int* __restrict__ r1, int* __restrict__ r2, int* __restrict__ bsum) {
    __shared__ int sd[256];
    int b = blockIdx.x, t = threadIdx.x;
    const int* cnt; int* out; int* bs; int n, cb;
    if (b < 118)      { cnt = c0; out = r0; bs = bsum;       n = N1; cb = b; }
    else if (b < 138) { cnt = c1; out = r1; bs = bsum + 128; n = N2; cb = b - 118; }
    else              { cnt = c2; out = r2; bs = bsum + 256; n = N3; cb = b - 138; }
    int base = cb * 1024 + t * 4;
    int v[4]; int s = 0;
    #pragma unroll
    for (int j = 0; j < 4; j++) { int i = base + j; v[j] = (i < n) ? cnt[i] : 0; s += v[j]; }
    sd[t] = s;
    __syncthreads();
    for (int off = 1; off < 256; off <<= 1) {
        int x = (t >= off) ? sd[t - off] : 0;
        __syncthreads();
        sd[t] += x;
        __syncthreads();
    }
    int run = sd[t] - s;
    #pragma unroll
    for (int j = 0; j < 4; j++) { int i = base + j; if (i < n) out[i] = run; run += v[j]; }
    if (t == 255) bs[cb] = sd[255];
}

__global__ __launch_bounds__(256) void scan_bsum_batch(int* __restrict__ bsum,
        int* __restrict__ r0, int* __restrict__ r1, int* __restrict__ r2) {
    __shared__ int sd[256];
    int l = blockIdx.x, t = threadIdx.x;
    int B = (l == 0) ? 118 : (l == 1 ? 20 : 4);
    int* bs = bsum + l * 128;
    int s = (t < B) ? bs[t] : 0;
    sd[t] = s;
    __syncthreads();
    for (int off = 1; off < 256; off <<= 1) {
        int x = (t >= off) ? sd[t - off] : 0;
        __syncthreads();
        sd[t] += x;
        __syncthreads();
    }
    if (t < B) bs[t] = sd[t] - s;
    if (t == 255) {
        if (l == 0) r0[N1] = sd[255];
        else if (l == 1) r1[N2] = sd[255];
        else r2[N3] = sd[255];
    }
}

__global__ void scan_add_batch(int* __restrict__ r0, int* __restrict__ r1,
                               int* __restrict__ r2, const int* __restrict__ bsum) {
    int i = blockIdx.x * blockDim.x + threadIdx.x;
    if (i < N1) r0[i] += bsum[i >> 10];
    else if (i < N1 + N2) { int j = i - N1; r1[j] += bsum[128 + (j >> 10)]; }
    else if (i < N1 + N2 + N3) { int j = i - N1 - N2; r2[j] += bsum[256 + (j >> 10)]; }
}

// ---- fallback: direct scatter fill (used only if workspace is small) ----
__global__ void csr_fill_batch(const int* __restrict__ s0, const int* __restrict__ d0,
                               const int* __restrict__ s1, const int* __restrict__ d1,
                               const int* __restrict__ s2, const int* __restrict__ d2,
                               int* __restrict__ c0, int* __restrict__ c1, int* __restrict__ c2,
                               const int* __restrict__ r0, const int* __restrict__ r1,
                               const int* __restrict__ r2, int* __restrict__ col0,
                               int* __restrict__ col1, int* __restrict__ col2) {
    int i = blockIdx.x * blockDim.x + threadIdx.x;
    if (i < E0) {
        int d = d0[i];
        col0[r0[d] + atomicSub(&c0[d], 1) - 1] = s0[i];
    } else if (i < E0 + E1) {
        int e = i - E0; int d = d1[e];
        col1[r1[d] + atomicSub(&c1[d], 1) - 1] = s1[e];
    } else if (i < E0 + E1 + E2) {
        int e = i - E0 - E1; int d = d2[e];
        col2[r2[d] + atomicSub(&c2[d], 1) - 1] = s2[e];
    }
}

// ---- bucketed fill phase A: append packed (src,dst) into per-bucket regions ----
// bucket = dst >> 7 (128 dsts per bucket); region base = rp[bucket<<7].
__global__ void csr_append_batch(const int* __restrict__ s0, const int* __restrict__ d0,
                                 const int* __restrict__ s1, const int* __restrict__ d1,
                                 const int* __restrict__ s2, const int* __restrict__ d2,
                                 const int* __restrict__ r0, const int* __restrict__ r1,
                                 const int* __restrict__ r2,
                                 int* __restrict__ cur0, int* __restrict__ cur1,
                                 int* __restrict__ cur2,
                                 uint2* __restrict__ pk0, uint2* __restrict__ pk1,
                                 uint2* __restrict__ pk2) {
    int i = blockIdx.x * blockDim.x + threadIdx.x;
    if (i < E0) {
        int d = d0[i]; int b = d >> 7;
        int base = r0[b << 7];
        int pos = atomicAdd(&cur0[b], 1);
        uint2 p; p.x = (unsigned)s0[i]; p.y = (unsigned)d;
        pk0[base + pos] = p;
    } else if (i < E0 + E1) {
        int e = i - E0; int d = d1[e]; int b = d >> 7;
        int base = r1[b << 7];
        int pos = atomicAdd(&cur1[b], 1);
        uint2 p; p.x = (unsigned)s1[e]; p.y = (unsigned)d;
        pk1[base + pos] = p;
    } else if (i < E0 + E1 + E2) {
        int e = i - E0 - E1; int d = d2[e]; int b = d >> 7;
        int base = r2[b << 7];
        int pos = atomicAdd(&cur2[b], 1);
        uint2 p; p.x = (unsigned)s2[e]; p.y = (unsigned)d;
        pk2[base + pos] = p;
    }
}

// ---- bucketed fill phase B: one workgroup per bucket, LDS slot counters ----
// Reads the bucket's packed region densely; writes col confined to one ~8KB
// region from a single CU -> full-line dirty, single writeback.
__global__ __launch_bounds__(256) void csr_bucket_fill(
        const int* __restrict__ r0, const int* __restrict__ r1, const int* __restrict__ r2,
        const uint2* __restrict__ pk0, const uint2* __restrict__ pk1,
        const uint2* __restrict__ pk2,
        int* __restrict__ col0, int* __restrict__ col1, int* __restrict__ col2) {
    __shared__ int lofs[128];
    int b = blockIdx.x;
    const int* rp; const uint2* pk; int* col; int lb, n;
    if (b < NB0)            { rp = r0; pk = pk0; col = col0; lb = b;             n = N1; }
    else if (b < NB0 + NB1) { rp = r1; pk = pk1; col = col1; lb = b - NB0;       n = N2; }
    else                    { rp = r2; pk = pk2; col = col2; lb = b - NB0 - NB1; n = N3; }
    int dlo = lb << 7;
    int dhi = min(dlo + 128, n);
    int base = rp[dlo];
    int cnt = rp[dhi] - base;
    int t = threadIdx.x;
    if (t < 128) {
        int dd = dlo + t;
        lofs[t] = (dd < dhi) ? (rp[dd] - base) : 0;
    }
    __syncthreads();
    for (int e = t; e < cnt; e += 256) {
        uint2 p = pk[base + e];
        int k = (int)p.y - dlo;
        int pos = atomicAdd(&lofs[k], 1);
        col[base + pos] = (int)p.x;
    }
}

// ================= gather-mean, scalar fallback (float input path) ==========
template <int DIN, typename T>
__global__ __launch_bounds__(256) void gather_mean(const T* __restrict__ h,
        const int* __restrict__ rp, const int* __restrict__ col,
        int n_dst, bf16* __restrict__ agg) {
    int gw = (blockIdx.x * blockDim.x + threadIdx.x) >> 6;
    int lane = threadIdx.x & 63;
    if (gw >= n_dst) return;
    int beg = rp[gw], end = rp[gw + 1];
    constexpr int VP = DIN / 64;
    float s[VP] = {};

    auto accum = [&](int srcn) {
        const T* hp = h + (size_t)srcn * DIN + lane * VP;
        if constexpr (sizeof(T) == 4) {  // float, VP==2
            float2 v = *(const float2*)hp;
            s[0] += v.x; s[1] += v.y;
        } else if constexpr (VP == 2) {  // bf16 x2
            union { unsigned u; unsigned short us[2]; } r;
            r.u = *(const unsigned*)hp;
            s[0] += bu2f(r.us[0]); s[1] += bu2f(r.us[1]);
        } else {  // bf16 x4
            union { uint2 u; unsigned short us[4]; } r;
            r.u = *(const uint2*)hp;
            #pragma unroll
            for (int j = 0; j < 4; j++) s[j] += bu2f(r.us[j]);
        }
    };

    int e = beg;
    for (; e + 3 < end; e += 4) {
        int a0 = col[e], a1 = col[e + 1], a2 = col[e + 2], a3 = col[e + 3];
        accum(a0); accum(a1); accum(a2); accum(a3);
    }
    for (; e < end; ++e) accum(col[e]);

    float inv = 1.f / fmaxf((float)(end - beg), 1.f);
    #pragma unroll
    for (int j = 0; j < VP; j++) s[j] *= inv;

    bf16* ap = agg + (size_t)gw * DIN + lane * VP;
    if constexpr (VP == 2) {
        ushort2 o; o.x = f2bu(s[0]); o.y = f2bu(s[1]);
        *(ushort2*)ap = o;
    } else {
        ushort4 o; o.x = f2bu(s[0]); o.y = f2bu(s[1]); o.z = f2bu(s[2]); o.w = f2bu(s[3]);
        *(ushort4*)ap = o;
    }
}

// ================= gather-mean, wide bf16 path =================
// One wave per dst node. Each lane loads 16B (8 bf16) -> G = DIN/8 lanes cover
// one row, R = 64/G rows (edges) gathered per load instruction. Partial sums
// are combined across the R lane-groups with a shfl_xor butterfly; lanes
// 0..G-1 store the final 16B each.
template <int DIN>
__global__ __launch_bounds__(256) void gather_mean_w(const bf16* __restrict__ h,
        const int* __restrict__ rp, const int* __restrict__ col,
        int n_dst, bf16* __restrict__ agg) {
    constexpr int G = DIN / 8;   // lanes per row (16 for D=128, 32 for D=256)
    constexpr int R = 64 / G;    // rows per iteration (4 / 2)
    int gw = (blockIdx.x * blockDim.x + threadIdx.x) >> 6;
    int lane = threadIdx.x & 63;
    if (gw >= n_dst) return;
    int beg = rp[gw], end = rp[gw + 1];
    int g = lane / G;            // group (edge slot)
    int p = lane & (G - 1);      // position within row

    float s[8] = {};

    auto accum = [&](const short8& v) {
        #pragma unroll
        for (int j = 0; j < 8; j++) s[j] += bu2f((unsigned short)v[j]);
    };

    int e = beg;
    // 2x unrolled main loop: 2*R rows in flight per wave
    for (; e + 2 * R <= end; e += 2 * R) {
        int sa = col[e + g];
        int sb = col[e + R + g];
        short8 va = load8(h + (size_t)sa * DIN + p * 8);
        short8 vb = load8(h + (size_t)sb * DIN + p * 8);
        accum(va); accum(vb);
    }
    for (; e + R <= end; e += R) {
        int sa = col[e + g];
        short8 va = load8(h + (size_t)sa * DIN + p * 8);
        accum(va);
    }
    if (e < end) {
        bool act = (e + g) < end;
        int sa = col[act ? (e + g) : beg];   // beg is valid whenever end>beg
        short8 va = load8(h + (size_t)sa * DIN + p * 8);
        if (act) accum(va);
    }

    // reduce partial sums across the R groups (butterfly keeps p fixed)
    #pragma unroll
    for (int m = G; m < 64; m <<= 1) {
        #pragma unroll
        for (int j = 0; j < 8; j++) s[j] += __shfl_xor(s[j], m, 64);
    }

    float inv = 1.f / fmaxf((float)(end - beg), 1.f);
    if (g == 0) {
        union { uint4 u; unsigned short us[8]; } o;
        #pragma unroll
        for (int j = 0; j < 8; j++) o.us[j] = f2bu(s[j] * inv);
        *(uint4*)(agg + (size_t)gw * DIN + p * 8) = o.u;
    }
}

// ================= fused MFMA SAGE GEMM =================
// C[M,Nstore] = relu?( A@Ws + Mn@Wn + b ) as K-concatenated bf16 MFMA GEMM.
// Block tile 128(m) x 128(n), 4 waves of 64x64, 16x16x32 MFMA, BK=32.
template <typename TA, typename TC, bool RELU>
__global__ __launch_bounds__(256) void gemm_mfma(
    const TA* __restrict__ A, const bf16* __restrict__ Mn,
    const bf16* __restrict__ Wst, const bf16* __restrict__ Wnt,
    const float* __restrict__ bias, TC* __restrict__ C,
    int M, int Nstore, int Npad, int K) {
    __shared__ short As[128][48];
    __shared__ short Bs[128][48];

    int tid = threadIdx.x;
    int m0 = blockIdx.x * 128;
    int n0 = blockIdx.y * 128;
    int lane = tid & 63, wid = tid >> 6;
    int wm = (wid & 1) * 64, wn = (wid >> 1) * 64;
    int l15 = lane & 15, quad = lane >> 4;

    float4v acc[4][4] = {};

    int nsteps = (2 * K) >> 5;
    int r = tid >> 2, c = (tid & 3) << 3;
    for (int s = 0; s < nsteps; ++s) {
        int ks = s << 5;
        bool self = ks < K;
        int ko = self ? ks : ks - K;
        #pragma unroll
        for (int it = 0; it < 2; ++it) {
            int rr = r + it * 64;
            // A-tile row
            {
                int gm = m0 + rr;
                short8 v = (short8)0;
                if (gm < M) {
                    if (self) v = load8(A  + (size_t)gm * K + ko + c);
                    else      v = load8(Mn + (size_t)gm * K + ko + c);
                }
                *(short8*)&As[rr][c] = v;
            }
            // B-tile row
            {
                int gn = n0 + rr;
                short8 w = (short8)0;
                if (gn < Npad) {
                    const bf16* Wp = self ? Wst : Wnt;
                    w = load8(Wp + (size_t)gn * K + ko + c);
                }
                *(short8*)&Bs[rr][c] = w;
            }
        }
        __syncthreads();
        short8 af[4], bfr[4];
        #pragma unroll
        for (int i = 0; i < 4; ++i)
            af[i] = *(const short8*)&As[wm + i * 16 + l15][quad * 8];
        #pragma unroll
        for (int j = 0; j < 4; ++j)
            bfr[j] = *(const short8*)&Bs[wn + j * 16 + l15][quad * 8];
        #pragma unroll
        for (int i = 0; i < 4; ++i)
            #pragma unroll
            for (int j = 0; j < 4; ++j)
                acc[i][j] = __builtin_amdgcn_mfma_f32_16x16x32_bf16(af[i], bfr[j], acc[i][j], 0, 0, 0);
        __syncthreads();
    }

    #pragma unroll
    for (int i = 0; i < 4; ++i) {
        #pragma unroll
        for (int j = 0; j < 4; ++j) {
            int gn = n0 + wn + j * 16 + l15;
            if (gn >= Nstore) continue;
            float bv = bias[gn];
            #pragma unroll
            for (int rr = 0; rr < 4; ++rr) {
                int gm = m0 + wm + i * 16 + quad * 4 + rr;
                if (gm >= M) continue;
                float v = acc[i][j][rr] + bv;
                if (RELU) v = fmaxf(v, 0.f);
                stv(&C[(size_t)gm * Nstore + gn], v);
            }
        }
    }
}

// ================= launch =================
extern "C" void kernel_launch(void* const* d_in, const int* in_sizes, int n_in,
                              void* d_out, int out_size, void* d_ws, size_t ws_size,
                              hipStream_t stream) {
    const float* x    = (const float*)d_in[0];
    const int*  src0 = (const int*)d_in[1];
    const int*  dst0 = (const int*)d_in[2];
    const int*  src1 = (const int*)d_in[3];
    const int*  dst1 = (const int*)d_in[4];
    const int*  src2 = (const int*)d_in[5];
    const int*  dst2 = (const int*)d_in[6];
    const float* Ws0 = (const float*)d_in[7];
    const float* Wn0 = (const float*)d_in[8];
    const float* b0  = (const float*)d_in[9];
    const float* Ws1 = (const float*)d_in[10];
    const float* Wn1 = (const float*)d_in[11];
    const float* b1  = (const float*)d_in[12];
    const float* Ws2 = (const float*)d_in[13];
    const float* Wn2 = (const float*)d_in[14];
    const float* b2  = (const float*)d_in[15];
    float* out = (float*)d_out;

    char* W = (char*)d_ws;
    // ---- persistent block (CSR + bsum + weights): [0, 9,676,032) ----
    int* cnt0  = (int*)(W + 0);              // 480,000
    int* cnt1  = (int*)(W + 480000);         //  80,000
    int* cnt2  = (int*)(W + 560000);         //  16,000   (memset [0,576,000) once)
    int* rp0   = (int*)(W + 576000);         // 480,004
    int* rp1   = (int*)(W + 1056004);        //  80,004
    int* rp2   = (int*)(W + 1136008);        //  16,004  (end 1,152,012; pad to 1,152,016)
    int* col0  = (int*)(W + 1152016);        // 7,200,000
    int* col1  = (int*)(W + 8352016);        //   800,000
    int* col2  = (int*)(W + 9152016);        //    80,000
    int* bsum  = (int*)(W + 9232016);        //     1,536 (3 x 128 ints)
    bf16* Wst0 = (bf16*)(W + 9233552);       //    65,536
    bf16* Wnt0 = (bf16*)(W + 9299088);       //    65,536
    bf16* Wst1 = (bf16*)(W + 9364624);       //   131,072
    bf16* Wnt1 = (bf16*)(W + 9495696);       //   131,072
    bf16* Wst2 = (bf16*)(W + 9626768);       //    24,576
    bf16* Wnt2 = (bf16*)(W + 9651344);       //    24,576  (end 9,675,920; pad to 9,676,032)

    const size_t BASE = 9676032;
    const bool use_xb = ws_size >= (size_t)205000000;
    bf16* xb = (bf16*)(W + BASE);                                  // 102,400,000 (use_xb only)
    size_t agg0_off = BASE + (use_xb ? 102400000 : 0);
    bf16* agg0 = (bf16*)(W + agg0_off);                            // 30,720,000
    bf16* h1   = (bf16*)(W + agg0_off + 30720000);                 // 61,440,000
    bf16* agg1 = (bf16*)(W + BASE);                                // 10,240,000 (xb/agg0 dead)
    bf16* h2   = (bf16*)(W + BASE + 10240000);                     // 10,240,000
    bf16* agg2 = (bf16*)(W + BASE + 20480000);                     //  2,048,000

    // ---- bucketed-fill staging (beyond the dense-path footprint) ----
    const bool bucketed = ws_size >= (size_t)227000000;
    int*  cur0 = (int*)(W + 210000000);      // 3,752  (938 ints)
    int*  cur1 = (int*)(W + 210003752);      //   628  (157 ints)
    int*  cur2 = (int*)(W + 210004380);      //   128  ( 32 ints)  memset 4,512
    uint2* pk0 = (uint2*)(W + 210004512);    // 14,400,000
    uint2* pk1 = (uint2*)(W + 224404512);    //  1,600,000
    uint2* pk2 = (uint2*)(W + 226004512);    //    160,000 (end 226,164,512)

    // ---- phase 1: conversions + batched CSR build ----
    hipMemsetAsync(W, 0, 576000, stream);  // all three cnt arrays
    if (bucketed) hipMemsetAsync(W + 210000000, 0, 4512, stream);  // bucket cursors
    if (use_xb) {
        int n8 = 400000 * D_IN / 8;  // 6,400,000
        convert_x<<<(n8 + 255) / 256, 256, 0, stream>>>(x, xb, n8);
    }
    wt_batch<<<(221184 + 255) / 256, 256, 0, stream>>>(Ws0, Wn0, Ws1, Wn1, Ws2, Wn2,
                                                       Wst0, Wnt0, Wst1, Wnt1, Wst2, Wnt2);
    const int ETOT = E0 + E1 + E2;
    hist_batch<<<(ETOT + 255) / 256, 256, 0, stream>>>(dst0, dst1, dst2, cnt0, cnt1, cnt2);
    scan_chunk_batch<<<142, 256, 0, stream>>>(cnt0, cnt1, cnt2, rp0, rp1, rp2, bsum);
    scan_bsum_batch<<<3, 256, 0, stream>>>(bsum, rp0, rp1, rp2);
    scan_add_batch<<<(N1 + N2 + N3 + 255) / 256, 256, 0, stream>>>(rp0, rp1, rp2, bsum);
    if (bucketed) {
        csr_append_batch<<<(ETOT + 255) / 256, 256, 0, stream>>>(
            src0, dst0, src1, dst1, src2, dst2, rp0, rp1, rp2,
            cur0, cur1, cur2, pk0, pk1, pk2);
        csr_bucket_fill<<<NB0 + NB1 + NB2, 256, 0, stream>>>(
            rp0, rp1, rp2, pk0, pk1, pk2, col0, col1, col2);
    } else {
        csr_fill_batch<<<(ETOT + 255) / 256, 256, 0, stream>>>(src0, dst0, src1, dst1, src2, dst2,
                                                               cnt0, cnt1, cnt2, rp0, rp1, rp2,
                                                               col0, col1, col2);
    }

    // ---- layer 0: 400000 -> 120000, K=128, relu ----
    if (use_xb) {
        gather_mean_w<D_IN><<<(N1 + 3) / 4, 256, 0, stream>>>(xb, rp0, col0, N1, agg0);
        dim3 grid((N1 + 127) / 128, 2);
        gemm_mfma<bf16, bf16, true><<<grid, 256, 0, stream>>>(xb, agg0, Wst0, Wnt0, b0, h1, N1, 256, 256, 128);
    } else {
        gather_mean<D_IN, float><<<(N1 + 3) / 4, 256, 0, stream>>>(x, rp0, col0, N1, agg0);
        dim3 grid((N1 + 127) / 128, 2);
        gemm_mfma<float, bf16, true><<<grid, 256, 0, stream>>>(x, agg0, Wst0, Wnt0, b0, h1, N1, 256, 256, 128);
    }

    // ---- layer 1: 120000 -> 20000, K=256, relu ----
    gather_mean_w<D_HID><<<(N2 + 3) / 4, 256, 0, stream>>>(h1, rp1, col1, N2, agg1);
    {
        dim3 grid((N2 + 127) / 128, 2);
        gemm_mfma<bf16, bf16, true><<<grid, 256, 0, stream>>>(h1, agg1, Wst1, Wnt1, b1, h2, N2, 256, 256, 256);
    }

    // ---- layer 2: 20000 -> 4000, K=256, no relu ----
    gather_mean_w<D_HID><<<(N3 + 3) / 4, 256, 0, stream>>>(h2, rp2, col2, N3, agg2);
    {
        dim3 grid((N3 + 127) / 128, 1);
        gemm_mfma<bf16, float, false><<<grid, 256, 0, stream>>>(h2, agg2, Wst2, Wnt2, b2, out, N3, 47, 48, 256);
    }
}

// Round 3
// 682.545 us; speedup vs baseline: 1.6025x; 1.6025x over previous
//
#include <hip/hip_runtime.h>
#include <hip/hip_bf16.h>

typedef __hip_bfloat16 bf16;
typedef __attribute__((ext_vector_type(8))) short short8;
typedef __attribute__((ext_vector_type(4))) float float4v;

// ---- problem constants ----
#define N1 120000
#define N2 20000
#define N3 4000
#define E0 1800000
#define E1 200000
#define E2 20000
#define D_IN 128
#define D_HID 256
#define D_OUT 47

__device__ __forceinline__ void stv(float* p, float v) { *p = v; }
__device__ __forceinline__ void stv(bf16* p, float v) { *p = __float2bfloat16(v); }

__device__ __forceinline__ unsigned short f2bu(float v) {
    union { bf16 h; unsigned short u; } c;
    c.h = __float2bfloat16(v);
    return c.u;
}
__device__ __forceinline__ short f2bs(float v) { return (short)f2bu(v); }
__device__ __forceinline__ float bu2f(unsigned short u) { return __uint_as_float(((unsigned)u) << 16); }

__device__ __forceinline__ short8 load8(const bf16* p) {
    union { uint4 u; short8 s; } r;
    r.u = *(const uint4*)p;
    return r.s;
}
__device__ __forceinline__ short8 load8(const float* p) {
    float4 a = *(const float4*)p;
    float4 b = *(const float4*)(p + 4);
    short8 s;
    s[0] = f2bs(a.x); s[1] = f2bs(a.y); s[2] = f2bs(a.z); s[3] = f2bs(a.w);
    s[4] = f2bs(b.x); s[5] = f2bs(b.y); s[6] = f2bs(b.z); s[7] = f2bs(b.w);
    return s;
}

// ================= x -> bf16 conversion =================
__global__ __launch_bounds__(256) void convert_x(const float* __restrict__ x,
                                                 bf16* __restrict__ xb, int n8) {
    int i = blockIdx.x * blockDim.x + threadIdx.x;
    if (i >= n8) return;
    const float* p = x + (size_t)i * 8;
    float4 a = *(const float4*)p;
    float4 b = *(const float4*)(p + 4);
    union { uint4 u; short s[8]; } o;
    o.s[0] = f2bs(a.x); o.s[1] = f2bs(a.y); o.s[2] = f2bs(a.z); o.s[3] = f2bs(a.w);
    o.s[4] = f2bs(b.x); o.s[5] = f2bs(b.y); o.s[6] = f2bs(b.z); o.s[7] = f2bs(b.w);
    *(uint4*)(xb + (size_t)i * 8) = o.u;
}

// ================= batched weight transpose+convert =================
// W[K][N] f32 -> Wt[Npad][K] bf16
__global__ void wt_batch(const float* W0s, const float* W0n, const float* W1s,
                         const float* W1n, const float* W2s, const float* W2n,
                         bf16* T0s, bf16* T0n, bf16* T1s, bf16* T1n, bf16* T2s, bf16* T2n) {
    int i = blockIdx.x * blockDim.x + threadIdx.x;
    const float* W; bf16* T; int K, N, j;
    if      (i <  32768) { W = W0s; T = T0s; K = 128; N = 256; j = i; }
    else if (i <  65536) { W = W0n; T = T0n; K = 128; N = 256; j = i - 32768; }
    else if (i < 131072) { W = W1s; T = T1s; K = 256; N = 256; j = i - 65536; }
    else if (i < 196608) { W = W1n; T = T1n; K = 256; N = 256; j = i - 131072; }
    else if (i < 208896) { W = W2s; T = T2s; K = 256; N = 47;  j = i - 196608; }
    else if (i < 221184) { W = W2n; T = T2n; K = 256; N = 47;  j = i - 208896; }
    else return;
    int n = j / K, k = j - n * K;
    float v = (n < N) ? W[(size_t)k * N + n] : 0.f;
    T[j] = __float2bfloat16(v);
}

// ================= batched CSR build =================
// hist with rank capture: rank[i] = arrival index of edge i within its dst.
__global__ void hist_rank_batch(const int* __restrict__ d0, const int* __restrict__ d1,
                                const int* __restrict__ d2, int* __restrict__ c0,
                                int* __restrict__ c1, int* __restrict__ c2,
                                int* __restrict__ rk0, int* __restrict__ rk1,
                                int* __restrict__ rk2) {
    int i = blockIdx.x * blockDim.x + threadIdx.x;
    if (i < E0) {
        rk0[i] = atomicAdd(&c0[d0[i]], 1);
    } else if (i < E0 + E1) {
        int e = i - E0;
        rk1[e] = atomicAdd(&c1[d1[e]], 1);
    } else if (i < E0 + E1 + E2) {
        int e = i - E0 - E1;
        rk2[e] = atomicAdd(&c2[d2[e]], 1);
    }
}

// fallback hist (no rank) for small-workspace path
__global__ void hist_batch(const int* __restrict__ d0, const int* __restrict__ d1,
                           const int* __restrict__ d2, int* __restrict__ c0,
                           int* __restrict__ c1, int* __restrict__ c2) {
    int i = blockIdx.x * blockDim.x + threadIdx.x;
    if (i < E0) atomicAdd(&c0[d0[i]], 1);
    else if (i < E0 + E1) atomicAdd(&c1[d1[i - E0]], 1);
    else if (i < E0 + E1 + E2) atomicAdd(&c2[d2[i - E0 - E1]], 1);
}

// chunk=1024; layer chunk counts: 118 / 20 / 4 -> 142 blocks total
__global__ __launch_bounds__(256) void scan_chunk_batch(
    const int* __restrict__ c0, const int* __restrict__ c1, const int* __restrict__ c2,
    int* __restrict__ r0, int* __restrict__ r1, int* __restrict__ r2, int* __restrict__ bsum) {
    __shared__ int sd[256];
    int b = blockIdx.x, t = threadIdx.x;
    const int* cnt; int* out; int* bs; int n, cb;
    if (b < 118)      { cnt = c0; out = r0; bs = bsum;       n = N1; cb = b; }
    else if (b < 138) { cnt = c1; out = r1; bs = bsum + 128; n = N2; cb = b - 118; }
    else              { cnt = c2; out = r2; bs = bsum + 256; n = N3; cb = b - 138; }
    int base = cb * 1024 + t * 4;
    int v[4]; int s = 0;
    #pragma unroll
    for (int j = 0; j < 4; j++) { int i = base + j; v[j] = (i < n) ? cnt[i] : 0; s += v[j]; }
    sd[t] = s;
    __syncthreads();
    for (int off = 1; off < 256; off <<= 1) {
        int x = (t >= off) ? sd[t - off] : 0;
        __syncthreads();
        sd[t] += x;
        __syncthreads();
    }
    int run = sd[t] - s;
    #pragma unroll
    for (int j = 0; j < 4; j++) { int i = base + j; if (i < n) out[i] = run; run += v[j]; }
    if (t == 255) bs[cb] = sd[255];
}

__global__ __launch_bounds__(256) void scan_bsum_batch(int* __restrict__ bsum,
        int* __restrict__ r0, int* __restrict__ r1, int* __restrict__ r2) {
    __shared__ int sd[256];
    int l = blockIdx.x, t = threadIdx.x;
    int B = (l == 0) ? 118 : (l == 1 ? 20 : 4);
    int* bs = bsum + l * 128;
    int s = (t < B) ? bs[t] : 0;
    sd[t] = s;
    __syncthreads();
    for (int off = 1; off < 256; off <<= 1) {
        int x = (t >= off) ? sd[t - off] : 0;
        __syncthreads();
        sd[t] += x;
        __syncthreads();
    }
    if (t < B) bs[t] = sd[t] - s;
    if (t == 255) {
        if (l == 0) r0[N1] = sd[255];
        else if (l == 1) r1[N2] = sd[255];
        else r2[N3] = sd[255];
    }
}

__global__ void scan_add_batch(int* __restrict__ r0, int* __restrict__ r1,
                               int* __restrict__ r2, const int* __restrict__ bsum) {
    int i = blockIdx.x * blockDim.x + threadIdx.x;
    if (i < N1) r0[i] += bsum[i >> 10];
    else if (i < N1 + N2) { int j = i - N1; r1[j] += bsum[128 + (j >> 10)]; }
    else if (i < N1 + N2 + N3) { int j = i - N1 - N2; r2[j] += bsum[256 + (j >> 10)]; }
}

// atomic-free fill: pos = rp[d] + rank[i]
__global__ void csr_fill_rank(const int* __restrict__ s0, const int* __restrict__ d0,
                              const int* __restrict__ s1, const int* __restrict__ d1,
                              const int* __restrict__ s2, const int* __restrict__ d2,
                              const int* __restrict__ rk0, const int* __restrict__ rk1,
                              const int* __restrict__ rk2,
                              const int* __restrict__ r0, const int* __restrict__ r1,
                              const int* __restrict__ r2, int* __restrict__ col0,
                              int* __restrict__ col1, int* __restrict__ col2) {
    int i = blockIdx.x * blockDim.x + threadIdx.x;
    if (i < E0) {
        col0[r0[d0[i]] + rk0[i]] = s0[i];
    } else if (i < E0 + E1) {
        int e = i - E0;
        col1[r1[d1[e]] + rk1[e]] = s1[e];
    } else if (i < E0 + E1 + E2) {
        int e = i - E0 - E1;
        col2[r2[d2[e]] + rk2[e]] = s2[e];
    }
}

// fallback: countdown scatter fill (small workspace)
__global__ void csr_fill_batch(const int* __restrict__ s0, const int* __restrict__ d0,
                               const int* __restrict__ s1, const int* __restrict__ d1,
                               const int* __restrict__ s2, const int* __restrict__ d2,
                               int* __restrict__ c0, int* __restrict__ c1, int* __restrict__ c2,
                               const int* __restrict__ r0, const int* __restrict__ r1,
                               const int* __restrict__ r2, int* __restrict__ col0,
                               int* __restrict__ col1, int* __restrict__ col2) {
    int i = blockIdx.x * blockDim.x + threadIdx.x;
    if (i < E0) {
        int d = d0[i];
        col0[r0[d] + atomicSub(&c0[d], 1) - 1] = s0[i];
    } else if (i < E0 + E1) {
        int e = i - E0; int d = d1[e];
        col1[r1[d] + atomicSub(&c1[d], 1) - 1] = s1[e];
    } else if (i < E0 + E1 + E2) {
        int e = i - E0 - E1; int d = d2[e];
        col2[r2[d] + atomicSub(&c2[d], 1) - 1] = s2[e];
    }
}

// ================= gather-mean, scalar fallback (float input path) ==========
template <int DIN, typename T>
__global__ __launch_bounds__(256) void gather_mean(const T* __restrict__ h,
        const int* __restrict__ rp, const int* __restrict__ col,
        int n_dst, bf16* __restrict__ agg) {
    int gw = (blockIdx.x * blockDim.x + threadIdx.x) >> 6;
    int lane = threadIdx.x & 63;
    if (gw >= n_dst) return;
    int beg = rp[gw], end = rp[gw + 1];
    constexpr int VP = DIN / 64;
    float s[VP] = {};

    auto accum = [&](int srcn) {
        const T* hp = h + (size_t)srcn * DIN + lane * VP;
        if constexpr (sizeof(T) == 4) {  // float, VP==2
            float2 v = *(const float2*)hp;
            s[0] += v.x; s[1] += v.y;
        } else if constexpr (VP == 2) {  // bf16 x2
            union { unsigned u; unsigned short us[2]; } r;
            r.u = *(const unsigned*)hp;
            s[0] += bu2f(r.us[0]); s[1] += bu2f(r.us[1]);
        } else {  // bf16 x4
            union { uint2 u; unsigned short us[4]; } r;
            r.u = *(const uint2*)hp;
            #pragma unroll
            for (int j = 0; j < 4; j++) s[j] += bu2f(r.us[j]);
        }
    };

    int e = beg;
    for (; e + 3 < end; e += 4) {
        int a0 = col[e], a1 = col[e + 1], a2 = col[e + 2], a3 = col[e + 3];
        accum(a0); accum(a1); accum(a2); accum(a3);
    }
    for (; e < end; ++e) accum(col[e]);

    float inv = 1.f / fmaxf((float)(end - beg), 1.f);
    #pragma unroll
    for (int j = 0; j < VP; j++) s[j] *= inv;

    bf16* ap = agg + (size_t)gw * DIN + lane * VP;
    if constexpr (VP == 2) {
        ushort2 o; o.x = f2bu(s[0]); o.y = f2bu(s[1]);
        *(ushort2*)ap = o;
    } else {
        ushort4 o; o.x = f2bu(s[0]); o.y = f2bu(s[1]); o.z = f2bu(s[2]); o.w = f2bu(s[3]);
        *(ushort4*)ap = o;
    }
}

// ================= gather-mean, wide bf16 path =================
// One wave per dst node. Each lane loads 16B (8 bf16) -> G = DIN/8 lanes cover
// one row, R = 64/G rows (edges) gathered per load instruction. Partial sums
// are combined across the R lane-groups with a shfl_xor butterfly; lanes
// 0..G-1 store the final 16B each.
template <int DIN>
__global__ __launch_bounds__(256) void gather_mean_w(const bf16* __restrict__ h,
        const int* __restrict__ rp, const int* __restrict__ col,
        int n_dst, bf16* __restrict__ agg) {
    constexpr int G = DIN / 8;   // lanes per row (16 for D=128, 32 for D=256)
    constexpr int R = 64 / G;    // rows per iteration (4 / 2)
    int gw = (blockIdx.x * blockDim.x + threadIdx.x) >> 6;
    int lane = threadIdx.x & 63;
    if (gw >= n_dst) return;
    int beg = rp[gw], end = rp[gw + 1];
    int g = lane / G;            // group (edge slot)
    int p = lane & (G - 1);      // position within row

    float s[8] = {};

    auto accum = [&](const short8& v) {
        #pragma unroll
        for (int j = 0; j < 8; j++) s[j] += bu2f((unsigned short)v[j]);
    };

    int e = beg;
    // 2x unrolled main loop: 2*R rows in flight per wave
    for (; e + 2 * R <= end; e += 2 * R) {
        int sa = col[e + g];
        int sb = col[e + R + g];
        short8 va = load8(h + (size_t)sa * DIN + p * 8);
        short8 vb = load8(h + (size_t)sb * DIN + p * 8);
        accum(va); accum(vb);
    }
    for (; e + R <= end; e += R) {
        int sa = col[e + g];
        short8 va = load8(h + (size_t)sa * DIN + p * 8);
        accum(va);
    }
    if (e < end) {
        bool act = (e + g) < end;
        int sa = col[act ? (e + g) : beg];   // beg is valid whenever end>beg
        short8 va = load8(h + (size_t)sa * DIN + p * 8);
        if (act) accum(va);
    }

    // reduce partial sums across the R groups (butterfly keeps p fixed)
    #pragma unroll
    for (int m = G; m < 64; m <<= 1) {
        #pragma unroll
        for (int j = 0; j < 8; j++) s[j] += __shfl_xor(s[j], m, 64);
    }

    float inv = 1.f / fmaxf((float)(end - beg), 1.f);
    if (g == 0) {
        union { uint4 u; unsigned short us[8]; } o;
        #pragma unroll
        for (int j = 0; j < 8; j++) o.us[j] = f2bu(s[j] * inv);
        *(uint4*)(agg + (size_t)gw * DIN + p * 8) = o.u;
    }
}

// ================= fused MFMA SAGE GEMM =================
// C[M,Nstore] = relu?( A@Ws + Mn@Wn + b ) as K-concatenated bf16 MFMA GEMM.
// Block tile 128(m) x 128(n), 4 waves of 64x64, 16x16x32 MFMA, BK=32.
template <typename TA, typename TC, bool RELU>
__global__ __launch_bounds__(256) void gemm_mfma(
    const TA* __restrict__ A, const bf16* __restrict__ Mn,
    const bf16* __restrict__ Wst, const bf16* __restrict__ Wnt,
    const float* __restrict__ bias, TC* __restrict__ C,
    int M, int Nstore, int Npad, int K) {
    __shared__ short As[128][48];
    __shared__ short Bs[128][48];

    int tid = threadIdx.x;
    int m0 = blockIdx.x * 128;
    int n0 = blockIdx.y * 128;
    int lane = tid & 63, wid = tid >> 6;
    int wm = (wid & 1) * 64, wn = (wid >> 1) * 64;
    int l15 = lane & 15, quad = lane >> 4;

    float4v acc[4][4] = {};

    int nsteps = (2 * K) >> 5;
    int r = tid >> 2, c = (tid & 3) << 3;
    for (int s = 0; s < nsteps; ++s) {
        int ks = s << 5;
        bool self = ks < K;
        int ko = self ? ks : ks - K;
        #pragma unroll
        for (int it = 0; it < 2; ++it) {
            int rr = r + it * 64;
            // A-tile row
            {
                int gm = m0 + rr;
                short8 v = (short8)0;
                if (gm < M) {
                    if (self) v = load8(A  + (size_t)gm * K + ko + c);
                    else      v = load8(Mn + (size_t)gm * K + ko + c);
                }
                *(short8*)&As[rr][c] = v;
            }
            // B-tile row
            {
                int gn = n0 + rr;
                short8 w = (short8)0;
                if (gn < Npad) {
                    const bf16* Wp = self ? Wst : Wnt;
                    w = load8(Wp + (size_t)gn * K + ko + c);
                }
                *(short8*)&Bs[rr][c] = w;
            }
        }
        __syncthreads();
        short8 af[4], bfr[4];
        #pragma unroll
        for (int i = 0; i < 4; ++i)
            af[i] = *(const short8*)&As[wm + i * 16 + l15][quad * 8];
        #pragma unroll
        for (int j = 0; j < 4; ++j)
            bfr[j] = *(const short8*)&Bs[wn + j * 16 + l15][quad * 8];
        #pragma unroll
        for (int i = 0; i < 4; ++i)
            #pragma unroll
            for (int j = 0; j < 4; ++j)
                acc[i][j] = __builtin_amdgcn_mfma_f32_16x16x32_bf16(af[i], bfr[j], acc[i][j], 0, 0, 0);
        __syncthreads();
    }

    #pragma unroll
    for (int i = 0; i < 4; ++i) {
        #pragma unroll
        for (int j = 0; j < 4; ++j) {
            int gn = n0 + wn + j * 16 + l15;
            if (gn >= Nstore) continue;
            float bv = bias[gn];
            #pragma unroll
            for (int rr = 0; rr < 4; ++rr) {
                int gm = m0 + wm + i * 16 + quad * 4 + rr;
                if (gm >= M) continue;
                float v = acc[i][j][rr] + bv;
                if (RELU) v = fmaxf(v, 0.f);
                stv(&C[(size_t)gm * Nstore + gn], v);
            }
        }
    }
}

// ================= launch =================
extern "C" void kernel_launch(void* const* d_in, const int* in_sizes, int n_in,
                              void* d_out, int out_size, void* d_ws, size_t ws_size,
                              hipStream_t stream) {
    const float* x    = (const float*)d_in[0];
    const int*  src0 = (const int*)d_in[1];
    const int*  dst0 = (const int*)d_in[2];
    const int*  src1 = (const int*)d_in[3];
    const int*  dst1 = (const int*)d_in[4];
    const int*  src2 = (const int*)d_in[5];
    const int*  dst2 = (const int*)d_in[6];
    const float* Ws0 = (const float*)d_in[7];
    const float* Wn0 = (const float*)d_in[8];
    const float* b0  = (const float*)d_in[9];
    const float* Ws1 = (const float*)d_in[10];
    const float* Wn1 = (const float*)d_in[11];
    const float* b1  = (const float*)d_in[12];
    const float* Ws2 = (const float*)d_in[13];
    const float* Wn2 = (const float*)d_in[14];
    const float* b2  = (const float*)d_in[15];
    float* out = (float*)d_out;

    char* W = (char*)d_ws;
    // ---- persistent block (CSR + bsum + weights): [0, 9,676,032) ----
    int* cnt0  = (int*)(W + 0);              // 480,000
    int* cnt1  = (int*)(W + 480000);         //  80,000
    int* cnt2  = (int*)(W + 560000);         //  16,000   (memset [0,576,000) once)
    int* rp0   = (int*)(W + 576000);         // 480,004
    int* rp1   = (int*)(W + 1056004);        //  80,004
    int* rp2   = (int*)(W + 1136008);        //  16,004  (end 1,152,012; pad to 1,152,016)
    int* col0  = (int*)(W + 1152016);        // 7,200,000
    int* col1  = (int*)(W + 8352016);        //   800,000
    int* col2  = (int*)(W + 9152016);        //    80,000
    int* bsum  = (int*)(W + 9232016);        //     1,536 (3 x 128 ints)
    bf16* Wst0 = (bf16*)(W + 9233552);       //    65,536
    bf16* Wnt0 = (bf16*)(W + 9299088);       //    65,536
    bf16* Wst1 = (bf16*)(W + 9364624);       //   131,072
    bf16* Wnt1 = (bf16*)(W + 9495696);       //   131,072
    bf16* Wst2 = (bf16*)(W + 9626768);       //    24,576
    bf16* Wnt2 = (bf16*)(W + 9651344);       //    24,576  (end 9,675,920; pad to 9,676,032)

    const size_t BASE = 9676032;
    const bool use_xb = ws_size >= (size_t)205000000;
    bf16* xb = (bf16*)(W + BASE);                                  // 102,400,000 (use_xb only)
    size_t agg0_off = BASE + (use_xb ? 102400000 : 0);
    bf16* agg0 = (bf16*)(W + agg0_off);                            // 30,720,000
    bf16* h1   = (bf16*)(W + agg0_off + 30720000);                 // 61,440,000
    bf16* agg1 = (bf16*)(W + BASE);                                // 10,240,000 (xb/agg0 dead)
    bf16* h2   = (bf16*)(W + BASE + 10240000);                     // 10,240,000
    bf16* agg2 = (bf16*)(W + BASE + 20480000);                     //  2,048,000

    // ---- rank staging (beyond the dense-path footprint) ----
    const bool ranked = ws_size >= (size_t)219000000;
    int* rk0 = (int*)(W + 210000000);        // 7,200,000
    int* rk1 = (int*)(W + 217200000);        //   800,000
    int* rk2 = (int*)(W + 218000000);        //    80,000 (end 218,080,000)

    // ---- phase 1: conversions + batched CSR build ----
    hipMemsetAsync(W, 0, 576000, stream);  // all three cnt arrays
    if (use_xb) {
        int n8 = 400000 * D_IN / 8;  // 6,400,000
        convert_x<<<(n8 + 255) / 256, 256, 0, stream>>>(x, xb, n8);
    }
    wt_batch<<<(221184 + 255) / 256, 256, 0, stream>>>(Ws0, Wn0, Ws1, Wn1, Ws2, Wn2,
                                                       Wst0, Wnt0, Wst1, Wnt1, Wst2, Wnt2);
    const int ETOT = E0 + E1 + E2;
    if (ranked) {
        hist_rank_batch<<<(ETOT + 255) / 256, 256, 0, stream>>>(dst0, dst1, dst2,
                                                                cnt0, cnt1, cnt2,
                                                                rk0, rk1, rk2);
    } else {
        hist_batch<<<(ETOT + 255) / 256, 256, 0, stream>>>(dst0, dst1, dst2, cnt0, cnt1, cnt2);
    }
    scan_chunk_batch<<<142, 256, 0, stream>>>(cnt0, cnt1, cnt2, rp0, rp1, rp2, bsum);
    scan_bsum_batch<<<3, 256, 0, stream>>>(bsum, rp0, rp1, rp2);
    scan_add_batch<<<(N1 + N2 + N3 + 255) / 256, 256, 0, stream>>>(rp0, rp1, rp2, bsum);
    if (ranked) {
        csr_fill_rank<<<(ETOT + 255) / 256, 256, 0, stream>>>(src0, dst0, src1, dst1, src2, dst2,
                                                              rk0, rk1, rk2, rp0, rp1, rp2,
                                                              col0, col1, col2);
    } else {
        csr_fill_batch<<<(ETOT + 255) / 256, 256, 0, stream>>>(src0, dst0, src1, dst1, src2, dst2,
                                                               cnt0, cnt1, cnt2, rp0, rp1, rp2,
                                                               col0, col1, col2);
    }

    // ---- layer 0: 400000 -> 120000, K=128, relu ----
    if (use_xb) {
        gather_mean_w<D_IN><<<(N1 + 3) / 4, 256, 0, stream>>>(xb, rp0, col0, N1, agg0);
        dim3 grid((N1 + 127) / 128, 2);
        gemm_mfma<bf16, bf16, true><<<grid, 256, 0, stream>>>(xb, agg0, Wst0, Wnt0, b0, h1, N1, 256, 256, 128);
    } else {
        gather_mean<D_IN, float><<<(N1 + 3) / 4, 256, 0, stream>>>(x, rp0, col0, N1, agg0);
        dim3 grid((N1 + 127) / 128, 2);
        gemm_mfma<float, bf16, true><<<grid, 256, 0, stream>>>(x, agg0, Wst0, Wnt0, b0, h1, N1, 256, 256, 128);
    }

    // ---- layer 1: 120000 -> 20000, K=256, relu ----
    gather_mean_w<D_HID><<<(N2 + 3) / 4, 256, 0, stream>>>(h1, rp1, col1, N2, agg1);
    {
        dim3 grid((N2 + 127) / 128, 2);
        gemm_mfma<bf16, bf16, true><<<grid, 256, 0, stream>>>(h1, agg1, Wst1, Wnt1, b1, h2, N2, 256, 256, 256);
    }

    // ---- layer 2: 20000 -> 4000, K=256, no relu ----
    gather_mean_w<D_HID><<<(N3 + 3) / 4, 256, 0, stream>>>(h2, rp2, col2, N3, agg2);
    {
        dim3 grid((N3 + 127) / 128, 1);
        gemm_mfma<bf16, float, false><<<grid, 256, 0, stream>>>(h2, agg2, Wst2, Wnt2, b2, out, N3, 47, 48, 256);
    }
}